// Round 2
// baseline (158.139 us; speedup 1.0000x reference)
//
#include <hip/hip_runtime.h>

// HydrophobicPairs: E[b,l] = h[seq[b,l]] * sum_k h[seq[b, j_idx[b,l,k]]] * g(r[b,l,k])
// g(r) = exp(-(r_c - r_peak)^2 / (2 sigma^2)) * (r < md - 1e-4)
// B=32, L=8192, K=64, NUM_AA=20.
//
// R10: R9 proved per-wave MLP is NOT the lever (12 loads/wave in flight,
// loads-only vmcnt queue -> dur unchanged at ~45us, ingress pinned at
// ~4.9 B/cyc/CU). The overlooked knob: grid=512 on 256 CUs capped occupancy
// at 2 blocks/CU = 4 waves/SIMD for ALL of R2-R9. LDS (34 KB/block) allows
// 4 blocks/CU = 2048 threads = 100% thread occupancy. This round: one
// variable — RPB 512->256, grid 1024, __launch_bounds__(512,8), DEPTH=3 so
// VGPR<=64 holds for 8 waves/SIMD. Same h_row gather, same register staging
// with hand-counted vmcnt on a loads-only queue.

#define BB 32
#define LL 8192
#define KK 64
#define TPB 512
#define RPB 256          // rows per block -> 1024 blocks, 4/CU, 32 waves/CU
#define NWAVE 8
#define NCHUNK 8         // 8 chunks x 4 rows = 32 rows per wave
#define DEPTH 3          // chunks in flight per wave (6 loads, 6 KB)

typedef float f32x4 __attribute__((ext_vector_type(4)));
typedef int   i32x4 __attribute__((ext_vector_type(4)));

// Sum across each 16-lane row via DPP row_shr (VALU-only). bound_ctrl=1
// zero-fills. Result lands in lane 15 of each 16-lane group.
__device__ __forceinline__ float row16_sum(float x) {
    x += __int_as_float(__builtin_amdgcn_mov_dpp(__float_as_int(x), 0x111, 0xF, 0xF, true)); // row_shr:1
    x += __int_as_float(__builtin_amdgcn_mov_dpp(__float_as_int(x), 0x112, 0xF, 0xF, true)); // row_shr:2
    x += __int_as_float(__builtin_amdgcn_mov_dpp(__float_as_int(x), 0x114, 0xF, 0xF, true)); // row_shr:4
    x += __int_as_float(__builtin_amdgcn_mov_dpp(__float_as_int(x), 0x118, 0xF, 0xF, true)); // row_shr:8
    return x;
}

// Issue one chunk's pair of 16 B/lane loads into register staging.
// volatile asm: ordered among themselves and vs the waitcnt asms below.
#define ISSUE(c) do {                                                          \
    asm volatile("global_load_dwordx4 %0, %1, off"                             \
                 : "=v"(rs[c]) : "v"(rlane + (c) * 256));                      \
    asm volatile("global_load_dwordx4 %0, %1, off"                             \
                 : "=v"(js[c]) : "v"(jlane + (c) * 256));                      \
} while (0)

// Hand-counted wait on the loads-only vmcnt queue; sched_barrier(0) stops
// hipcc hoisting register-only consumers above the wait (rule #18).
#define WAITV(n) do {                                                          \
    asm volatile("s_waitcnt vmcnt(" #n ")" ::: "memory");                      \
    __builtin_amdgcn_sched_barrier(0);                                         \
} while (0)

__global__ __launch_bounds__(TPB, 8) void _HydrophobicPairs_58256936403302_kernel(
    const int*   __restrict__ seq,        // [B,L]
    const float* __restrict__ r,          // [B,L,K]
    const int*   __restrict__ j_idx,      // [B,L,K]
    const float* __restrict__ h,          // [20]
    const float* __restrict__ r_half_raw, // [1]
    const float* __restrict__ tau_hp_raw, // [1]
    const int*   __restrict__ max_dist,   // [1]
    float*       __restrict__ out)        // [B,L]
{
    __shared__ float h_row[LL];           // 32 KB
    __shared__ float res[NWAVE][32];      // 1 KB result stash (per-wave rows)

    const int tid  = threadIdx.x;
    const int wave = tid >> 6;
    const int lane = tid & 63;
    const int b     = blockIdx.x >> 5;    // 32 chunks of 256 rows per b
    const int lbase = (blockIdx.x & 31) * RPB;

    // Stage h[seq[b, :]] -> LDS (coalesced int4 reads; h is 80 B, L1-hot).
    const int4* seq4 = (const int4*)(seq + b * LL);
    #pragma unroll
    for (int i = 0; i < 4; ++i) {
        const int e4 = i * TPB + tid;     // 0..2047 int4s
        const int4 s = seq4[e4];
        ((float4*)h_row)[e4] = make_float4(h[s.x], h[s.y], h[s.z], h[s.w]);
    }

    // Runtime scalars (broadcast, cached).
    const float md     = (float)max_dist[0];
    const float r_peak = log1pf(expf(r_half_raw[0]));            // softplus
    const float sigma  = log1pf(expf(tau_hp_raw[0])) + 0.1f;
    const float nscale = -1.44269504f / (2.0f * sigma * sigma);  // -log2e/(2s^2)
    const float c1     = -2.0f * nscale * r_peak;
    const float c0     = nscale * r_peak * r_peak;
    const float vthr   = md - 1e-4f;

    // Barrier: h_row visible; compiler drains vmcnt to 0 here, so the asm
    // load queue below starts from a clean count.
    __syncthreads();

    // Per-wave stream: 32 rows at l0; chunk = 4 rows = 256 elems = 1 KB each
    // of r/j; lane covers elements [4*lane, 4*lane+4) of each chunk.
    const int l0 = lbase + wave * 32;
    const float* rlane = r     + (size_t)(b * LL + l0) * KK + (lane << 2);
    const int*   jlane = j_idx + (size_t)(b * LL + l0) * KK + (lane << 2);

    f32x4 rs[NCHUNK];                     // register staging (SROA'd: all
    i32x4 js[NCHUNK];                     // indices compile-time constant)

    // Prologue: chunks 0..DEPTH-1 in flight (6 loads, 6 KB/wave).
    #pragma unroll
    for (int p = 0; p < DEPTH; ++p) ISSUE(p);

    const int myrow = lane >> 4;          // 0..3 (row within chunk)
    const int klane = lane & 15;

    #pragma unroll
    for (int c = 0; c < NCHUNK; ++c) {
        // Loads retire in order; queue holds chunks c..c+DEPTH-1.
        // Wait N = 2*min(DEPTH-1, NCHUNK-1-c): chunk c's pair has landed.
        if      (c <= NCHUNK - DEPTH) WAITV(4);
        else if (c == NCHUNK - 2)     WAITV(2);
        else                          WAITV(0);

        // Refill the pipe immediately after the wait.
        if (c + DEPTH < NCHUNK) ISSUE(c + DEPTH);

        const f32x4 rc = rs[c];
        const i32x4 jc = js[c];

        float acc = 0.0f;
        #pragma unroll
        for (int u = 0; u < 4; ++u) {
            const float rv = rc[u];
            const unsigned j = (unsigned)jc[u] & (LL - 1);
            const float hj = h_row[j];                        // LDS gather
            const float uexp = fmaf(rv, fmaf(nscale, rv, c1), c0);
            float g = exp2f(uexp);                            // v_exp_f32
            g = (rv < vthr) ? g : 0.0f;                       // validity mask
            acc = fmaf(hj, g, acc);
        }

        acc = row16_sum(acc);             // sum over the 16 k-lanes

        // Stash in LDS (DS op: does not touch the vmcnt queue). Same-wave
        // LDS ops execute in order -> no barrier needed before the flush.
        if (klane == 15) res[wave][(c << 2) | myrow] = acc;
    }

    // Flush: one coalesced 128 B store per wave (32 rows).
    if (lane < 32) {
        const int lrow = l0 + lane;
        out[b * LL + lrow] = h_row[lrow] * res[wave][lane];
    }
}

extern "C" void kernel_launch(void* const* d_in, const int* in_sizes, int n_in,
                              void* d_out, int out_size, void* d_ws, size_t ws_size,
                              hipStream_t stream) {
    const int*   seq        = (const int*)d_in[0];
    const float* r          = (const float*)d_in[1];
    const int*   j_idx      = (const int*)d_in[2];
    const float* h          = (const float*)d_in[3];
    const float* r_half_raw = (const float*)d_in[4];
    const float* tau_hp_raw = (const float*)d_in[5];
    const int*   max_dist   = (const int*)d_in[6];
    float*       out        = (float*)d_out;

    // 1024 blocks x 512 threads: 4 blocks/CU (33 KB LDS each), 32 waves/CU.
    _HydrophobicPairs_58256936403302_kernel<<<dim3(BB * (LL / RPB)), dim3(TPB), 0, stream>>>(
        seq, r, j_idx, h, r_half_raw, tau_hp_raw, max_dist, out);
}

// Round 3
// 157.712 us; speedup vs baseline: 1.0027x; 1.0027x over previous
//
#include <hip/hip_runtime.h>

// HydrophobicPairs: E[b,l] = h[seq[b,l]] * sum_k h[seq[b, j_idx[b,l,k]]] * g(r[b,l,k])
// g(r) = exp(-(r_c - r_peak)^2 / (2 sigma^2)) * (r < md - 1e-4)
// B=32, L=8192, K=64, NUM_AA=20.
//
// R11: R8 (LDS-DMA), R9 (deep VGPR staging), R10 (2x occupancy) all pinned at
// ~47us / ~4.6 B/cyc/CU delivered reads. The cap is a shared service rate,
// invariant to wave count and queue depth. Corpus check: best read rate ever
// demonstrated on this chip is the m13 copy's read COMPONENT ~3.15 TB/s
// (6.29 TB/s counts read+write) -- and in that copy, reads at 5.1 B/cyc/CU ran
// CONCURRENTLY with writes at 5.1, so TCP/fabric sustains ~10 B/cyc combined.
// Last untested hypothesis: the read cap is per-RETURN-PATH (VGPR-return vs
// LDS-direct), not a single shared read limit. R8 ran pure DMA (4.4 B/cyc),
// R9/R10 pure VGPR (4.7) -- never both. This round: wave specialization.
// Waves 0-3 stream r/j via __builtin_nontemporal_load (VGPR path; nt skips L2
// allocation for read-once data). Waves 4-7 use R8's proven global_load_lds
// double-buffer (loads-only vmcnt queue, counted waits). If additive: ~32us.
// If flat: roofline argument is complete (depth/occupancy/path/cache-policy
// all individually null at 91% of the platform's demonstrated read rate).

#define BB 32
#define LL 8192
#define KK 64
#define TPB 512
#define RPB 512          // rows per block -> 512 blocks
#define NWAVE 8
#define NCHUNK 16        // 16 chunks x 4 rows = 64 rows per wave

typedef float f32x4 __attribute__((ext_vector_type(4)));
typedef int   i32x4 __attribute__((ext_vector_type(4)));

__device__ __forceinline__ void dma16(const void* g, void* l) {
    __builtin_amdgcn_global_load_lds(
        (const __attribute__((address_space(1))) void*)g,
        (__attribute__((address_space(3))) void*)l, 16, 0, 0);
}

// Sum across each 16-lane row via DPP row_shr (VALU-only). bound_ctrl=1
// zero-fills. Result lands in lane 15 of each 16-lane group.
__device__ __forceinline__ float row16_sum(float x) {
    x += __int_as_float(__builtin_amdgcn_mov_dpp(__float_as_int(x), 0x111, 0xF, 0xF, true)); // row_shr:1
    x += __int_as_float(__builtin_amdgcn_mov_dpp(__float_as_int(x), 0x112, 0xF, 0xF, true)); // row_shr:2
    x += __int_as_float(__builtin_amdgcn_mov_dpp(__float_as_int(x), 0x114, 0xF, 0xF, true)); // row_shr:4
    x += __int_as_float(__builtin_amdgcn_mov_dpp(__float_as_int(x), 0x118, 0xF, 0xF, true)); // row_shr:8
    return x;
}

// Per-chunk math: 4 elements/lane -> partial sum over this lane's k-slice,
// then reduce across the 16 k-lanes of each row.
__device__ __forceinline__ float chunk_acc(f32x4 rc, i32x4 jc, const float* h_row,
                                           float nscale, float c1, float c0,
                                           float vthr) {
    float acc = 0.0f;
    #pragma unroll
    for (int u = 0; u < 4; ++u) {
        const float rv = rc[u];
        const unsigned j = (unsigned)jc[u] & (LL - 1);
        const float hj = h_row[j];                        // LDS gather
        const float uexp = fmaf(rv, fmaf(nscale, rv, c1), c0);
        float g = exp2f(uexp);                            // v_exp_f32
        g = (rv < vthr) ? g : 0.0f;                       // validity mask
        acc = fmaf(hj, g, acc);
    }
    return row16_sum(acc);
}

__global__ __launch_bounds__(TPB, 6) void _HydrophobicPairs_58256936403302_kernel(
    const int*   __restrict__ seq,        // [B,L]
    const float* __restrict__ r,          // [B,L,K]
    const int*   __restrict__ j_idx,      // [B,L,K]
    const float* __restrict__ h,          // [20]
    const float* __restrict__ r_half_raw, // [1]
    const float* __restrict__ tau_hp_raw, // [1]
    const int*   __restrict__ max_dist,   // [1]
    float*       __restrict__ out)        // [B,L]
{
    __shared__ float h_row[LL];                          // 32 KB
    __shared__ float res[NWAVE][64];                     // 2 KB result stash
    __shared__ __align__(16) char sbuf[4][2][2048];      // 16 KB: DMA waves only

    const int tid  = threadIdx.x;
    const int wave = tid >> 6;
    const int lane = tid & 63;
    const int b     = blockIdx.x >> 4;    // 16 chunks of 512 rows per b
    const int lbase = (blockIdx.x & 15) * RPB;

    // Stage h[seq[b, :]] -> LDS (coalesced int4 reads; h is 80 B, L1-hot).
    const int4* seq4 = (const int4*)(seq + b * LL);
    #pragma unroll
    for (int i = 0; i < 4; ++i) {
        const int e4 = i * TPB + tid;     // 0..2047 int4s
        const int4 s = seq4[e4];
        ((float4*)h_row)[e4] = make_float4(h[s.x], h[s.y], h[s.z], h[s.w]);
    }

    // Runtime scalars (broadcast, cached).
    const float md     = (float)max_dist[0];
    const float r_peak = log1pf(expf(r_half_raw[0]));            // softplus
    const float sigma  = log1pf(expf(tau_hp_raw[0])) + 0.1f;
    const float nscale = -1.44269504f / (2.0f * sigma * sigma);  // -log2e/(2s^2)
    const float c1     = -2.0f * nscale * r_peak;
    const float c0     = nscale * r_peak * r_peak;
    const float vthr   = md - 1e-4f;

    // Barrier: h_row visible; compiler drains vmcnt to 0 here, so the DMA
    // waves' hand-counted queue below starts from a clean count.
    __syncthreads();

    const int l0 = lbase + wave * 64;     // 64 rows per wave
    const int myrow = lane >> 4;          // 0..3 (row within chunk)
    const int klane = lane & 15;

    if (wave < 4) {
        // ---- VGPR-return path, non-temporal (no L2 allocation) ----
        const f32x4* r4 = (const f32x4*)(r     + (size_t)(b * LL + l0) * KK) + lane;
        const i32x4* j4 = (const i32x4*)(j_idx + (size_t)(b * LL + l0) * KK) + lane;
        #pragma unroll
        for (int c = 0; c < NCHUNK; ++c) {
            const f32x4 rc = __builtin_nontemporal_load(r4 + c * 64);
            const i32x4 jc = __builtin_nontemporal_load(j4 + c * 64);
            const float acc = chunk_acc(rc, jc, h_row, nscale, c1, c0, vthr);
            if (klane == 15) res[wave][(c << 2) | myrow] = acc;
        }
    } else {
        // ---- LDS-direct DMA path (R8 structure, loads-only vmcnt queue) ----
        const int dw = wave - 4;
        const char* rg = (const char*)(r     + (size_t)(b * LL + l0) * KK) + lane * 16;
        const char* jg = (const char*)(j_idx + (size_t)(b * LL + l0) * KK) + lane * 16;

        // Prologue: chunks 0 and 1 in flight (4 DMA loads).
        dma16(rg + 0 * 1024, &sbuf[dw][0][0]);
        dma16(jg + 0 * 1024, &sbuf[dw][0][1024]);
        dma16(rg + 1 * 1024, &sbuf[dw][1][0]);
        dma16(jg + 1 * 1024, &sbuf[dw][1][1024]);

        #pragma unroll
        for (int c = 0; c < NCHUNK; ++c) {
            // In-order retirement, loads-only queue: entering iter c the queue
            // holds [pair(c), pair(c+1)] (refill for c+1 issued at iter c-1).
            // Wait for j_c: 2 newer ops, except the last iter (queue = [pair15]).
            if (c < NCHUNK - 1) asm volatile("s_waitcnt vmcnt(2)" ::: "memory");
            else                asm volatile("s_waitcnt vmcnt(0)" ::: "memory");
            __builtin_amdgcn_sched_barrier(0);

            const int slot = c & 1;
            const f32x4 rc = *(const f32x4*)(&sbuf[dw][slot][lane * 16]);
            const i32x4 jc = *(const i32x4*)(&sbuf[dw][slot][1024 + lane * 16]);
            // Data must be in VGPRs before the refill DMA overwrites this slot.
            asm volatile("s_waitcnt lgkmcnt(0)" ::: "memory");
            __builtin_amdgcn_sched_barrier(0);

            if (c + 2 < NCHUNK) {         // refill this slot with chunk c+2
                dma16(rg + (c + 2) * 1024, &sbuf[dw][slot][0]);
                dma16(jg + (c + 2) * 1024, &sbuf[dw][slot][1024]);
            }

            const float acc = chunk_acc(rc, jc, h_row, nscale, c1, c0, vthr);
            if (klane == 15) res[wave][(c << 2) | myrow] = acc;
        }
    }

    // Flush: one coalesced 256 B store per wave (its own 64 rows; same-wave
    // LDS ordering makes res[wave][*] visible without a barrier).
    const int lrow = l0 + lane;
    out[b * LL + lrow] = h_row[lrow] * res[wave][lane];
}

extern "C" void kernel_launch(void* const* d_in, const int* in_sizes, int n_in,
                              void* d_out, int out_size, void* d_ws, size_t ws_size,
                              hipStream_t stream) {
    const int*   seq        = (const int*)d_in[0];
    const float* r          = (const float*)d_in[1];
    const int*   j_idx      = (const int*)d_in[2];
    const float* h          = (const float*)d_in[3];
    const float* r_half_raw = (const float*)d_in[4];
    const float* tau_hp_raw = (const float*)d_in[5];
    const int*   max_dist   = (const int*)d_in[6];
    float*       out        = (float*)d_out;

    // 512 blocks x 512 threads: 50 KB LDS -> 3 blocks/CU, 24 waves/CU.
    _HydrophobicPairs_58256936403302_kernel<<<dim3(BB * (LL / RPB)), dim3(TPB), 0, stream>>>(
        seq, r, j_idx, h, r_half_raw, tau_hp_raw, max_dist, out);
}

// Round 4
// 154.223 us; speedup vs baseline: 1.0254x; 1.0226x over previous
//
#include <hip/hip_runtime.h>

// HydrophobicPairs: E[b,l] = h[seq[b,l]] * sum_k h[seq[b, j_idx[b,l,k]]] * g(r[b,l,k])
// g(r) = exp(-(r_c - r_peak)^2 / (2 sigma^2)) * (r < md - 1e-4)
// B=32, L=8192, K=64, NUM_AA=20.
//
// R12: attribution round. R11 (4 nt-VGPR waves + 4 DMA waves) = 41us, first
// movement after R8/R9/R10 all pinned at ~47us. R11 changed two variables:
// dual return-path AND nt cache policy. Working model for the ~5.3 B/cyc/CU
// cap: per-CU TCP MSHR pool (~64 outstanding cachelines x 64 B / ~770 cyc
// mixed L3/HBM latency) -- invariant to wave count and queue depth, exactly
// as observed. Under that model nt (allocation policy -> effective latency)
// can move throughput. This round: PURE nt-VGPR on all 8 waves, compiler-
// scheduled (R9 proved manual vmcnt/depth is a no-op on this kernel).
//   nt is the lever  -> ~38-41us or better; R13 stacks sc0/sc1 L1-bypass.
//   dual-path is it  -> back to ~46us; R13 returns to mixed, tuned ratio.
//   FETCH_SIZE watch -> if nt kills L3 retention, FETCH rises toward 134MB.

#define BB 32
#define LL 8192
#define KK 64
#define TPB 512
#define RPB 512          // rows per block -> 512 blocks, 2/CU resident
#define NWAVE 8
#define NCHUNK 16        // 16 chunks x 4 rows = 64 rows per wave

typedef float f32x4 __attribute__((ext_vector_type(4)));
typedef int   i32x4 __attribute__((ext_vector_type(4)));

// Sum across each 16-lane row via DPP row_shr (VALU-only). bound_ctrl=1
// zero-fills. Result lands in lane 15 of each 16-lane group.
__device__ __forceinline__ float row16_sum(float x) {
    x += __int_as_float(__builtin_amdgcn_mov_dpp(__float_as_int(x), 0x111, 0xF, 0xF, true)); // row_shr:1
    x += __int_as_float(__builtin_amdgcn_mov_dpp(__float_as_int(x), 0x112, 0xF, 0xF, true)); // row_shr:2
    x += __int_as_float(__builtin_amdgcn_mov_dpp(__float_as_int(x), 0x114, 0xF, 0xF, true)); // row_shr:4
    x += __int_as_float(__builtin_amdgcn_mov_dpp(__float_as_int(x), 0x118, 0xF, 0xF, true)); // row_shr:8
    return x;
}

__global__ __launch_bounds__(TPB, 4) void _HydrophobicPairs_58256936403302_kernel(
    const int*   __restrict__ seq,        // [B,L]
    const float* __restrict__ r,          // [B,L,K]
    const int*   __restrict__ j_idx,      // [B,L,K]
    const float* __restrict__ h,          // [20]
    const float* __restrict__ r_half_raw, // [1]
    const float* __restrict__ tau_hp_raw, // [1]
    const int*   __restrict__ max_dist,   // [1]
    float*       __restrict__ out)        // [B,L]
{
    __shared__ float h_row[LL];           // 32 KB
    __shared__ float res[NWAVE][64];      // 2 KB result stash (per-wave rows)

    const int tid  = threadIdx.x;
    const int wave = tid >> 6;
    const int lane = tid & 63;
    const int b     = blockIdx.x >> 4;    // 16 chunks of 512 rows per b
    const int lbase = (blockIdx.x & 15) * RPB;

    // Stage h[seq[b, :]] -> LDS (coalesced int4 reads; h is 80 B, L1-hot).
    const int4* seq4 = (const int4*)(seq + b * LL);
    #pragma unroll
    for (int i = 0; i < 4; ++i) {
        const int e4 = i * TPB + tid;     // 0..2047 int4s
        const int4 s = seq4[e4];
        ((float4*)h_row)[e4] = make_float4(h[s.x], h[s.y], h[s.z], h[s.w]);
    }

    // Runtime scalars (broadcast, cached).
    const float md     = (float)max_dist[0];
    const float r_peak = log1pf(expf(r_half_raw[0]));            // softplus
    const float sigma  = log1pf(expf(tau_hp_raw[0])) + 0.1f;
    const float nscale = -1.44269504f / (2.0f * sigma * sigma);  // -log2e/(2s^2)
    const float c1     = -2.0f * nscale * r_peak;
    const float c0     = nscale * r_peak * r_peak;
    const float vthr   = md - 1e-4f;

    __syncthreads();                      // h_row visible to all waves

    // Per-wave stream: 64 rows at l0; chunk = 4 rows = 256 elems = 1 KB each
    // of r/j; lane covers elements [4*lane, 4*lane+4) of each chunk.
    const int l0 = lbase + wave * 64;
    const f32x4* r4 = (const f32x4*)(r     + (size_t)(b * LL + l0) * KK) + lane;
    const i32x4* j4 = (const i32x4*)(j_idx + (size_t)(b * LL + l0) * KK) + lane;

    const int myrow = lane >> 4;          // 0..3 (row within chunk)
    const int klane = lane & 15;

    #pragma unroll
    for (int c = 0; c < NCHUNK; ++c) {
        const f32x4 rc = __builtin_nontemporal_load(r4 + c * 64);
        const i32x4 jc = __builtin_nontemporal_load(j4 + c * 64);

        float acc = 0.0f;
        #pragma unroll
        for (int u = 0; u < 4; ++u) {
            const float rv = rc[u];
            const unsigned j = (unsigned)jc[u] & (LL - 1);
            const float hj = h_row[j];                        // LDS gather
            const float uexp = fmaf(rv, fmaf(nscale, rv, c1), c0);
            float g = exp2f(uexp);                            // v_exp_f32
            g = (rv < vthr) ? g : 0.0f;                       // validity mask
            acc = fmaf(hj, g, acc);
        }

        acc = row16_sum(acc);             // sum over the 16 k-lanes

        if (klane == 15) res[wave][(c << 2) | myrow] = acc;
    }

    // Flush: one coalesced 256 B store per wave (its own 64 rows; same-wave
    // LDS ordering makes res[wave][*] visible without a barrier).
    const int lrow = l0 + lane;
    out[b * LL + lrow] = h_row[lrow] * res[wave][lane];
}

extern "C" void kernel_launch(void* const* d_in, const int* in_sizes, int n_in,
                              void* d_out, int out_size, void* d_ws, size_t ws_size,
                              hipStream_t stream) {
    const int*   seq        = (const int*)d_in[0];
    const float* r          = (const float*)d_in[1];
    const int*   j_idx      = (const int*)d_in[2];
    const float* h          = (const float*)d_in[3];
    const float* r_half_raw = (const float*)d_in[4];
    const float* tau_hp_raw = (const float*)d_in[5];
    const int*   max_dist   = (const int*)d_in[6];
    float*       out        = (float*)d_out;

    // 512 blocks x 512 threads: 2 blocks/CU (34 KB LDS each), 16 waves/CU.
    _HydrophobicPairs_58256936403302_kernel<<<dim3(BB * (LL / RPB)), dim3(TPB), 0, stream>>>(
        seq, r, j_idx, h, r_half_raw, tau_hp_raw, max_dist, out);
}